// Round 4
// baseline (21.957 us; speedup 1.0000x reference)
//
#include <hip/hip_runtime.h>
#include <math.h>

// ModularQTS: B=256, F=64, NT=8, NQ=6 (DQ=64), NA=3 (DA=8), DEG=4, NROTS=24, KLOC=2.
// One block per batch element. 512 threads = 8 waves; wave = ancilla index a,
// lane = main index q. State: 1 complex amplitude per thread in VGPRs.
// Wire w <-> bit (n-1-w) (MSB-first), matching reference _ap1/_ap2 reshapes.

__device__ __forceinline__ float bperm_f(int addr, float v) {
    return __int_as_float(__builtin_amdgcn_ds_bpermute(addr, __float_as_int(v)));
}

__global__ void __launch_bounds__(512)
qts_kernel(const float* __restrict__ x,      // (B,64,8)
           const float* __restrict__ Wp,     // (24,64)
           const float* __restrict__ bpj,    // (24,)
           const float* __restrict__ prep,   // (3,3,2)
           const float* __restrict__ sig,    // (5,)
           const float* __restrict__ qff,    // (24,)
           const float* __restrict__ Aoff,   // (5,6)
           const float* __restrict__ Boff,   // (5,6)
           const float* __restrict__ Ddiag,  // (5,4)
           const float* __restrict__ Wh,     // (3,5)
           const float* __restrict__ bh,     // (3,)
           float* __restrict__ out)          // (B,3)
{
    __shared__ float  xs[512];        // x[b] as [f][t]
    __shared__ float  wp[64 * 24];    // W_proj transposed [f][r]
    __shared__ float2 csA[8 * 24];    // cos/sin(ts/2), [t][r]
    __shared__ float2 csQ[24];        // cos/sin(qff/2)
    __shared__ float2 Vl[64];         // PREPARE V, [i][j]
    __shared__ float  Hd_[5][3];      // 2*D_diag[w][1..3]
    __shared__ float  HA_[5][6];
    __shared__ float  HB_[5][6];
    __shared__ float2 sl[8 * 64];     // state staging [a][q]
    __shared__ float  exps_[5];

    const int tid  = threadIdx.x;
    const int lane = tid & 63;
    const int wid  = tid >> 6;        // ancilla index a
    const int b    = blockIdx.x;

    // ---------------- setup ----------------
    if (tid < 128)
        ((float4*)xs)[tid] = ((const float4*)(x + b * 512))[tid];
    for (int e = tid; e < 24 * 64; e += 512) {
        int r = e >> 6, f = e & 63;
        wp[f * 24 + r] = Wp[e];
    }
    if (tid < 24) {
        float th = 0.5f * qff[tid];
        csQ[tid] = make_float2(cosf(th), sinf(th));
    }
    if (tid < 5) {
        #pragma unroll
        for (int i = 0; i < 3; ++i) Hd_[tid][i] = 2.f * Ddiag[tid * 4 + i + 1];
        #pragma unroll
        for (int j = 0; j < 6; ++j) { HA_[tid][j] = Aoff[tid * 6 + j]; HB_[tid][j] = Boff[tid * 6 + j]; }
    }
    if (tid < 8) {
        // Build PREPARE V (8x8), thread owns column `col`; gates mix row index.
        const int col = tid;
        float vr[8], vi[8];
        #pragma unroll
        for (int r2 = 0; r2 < 8; ++r2) { vr[r2] = (r2 == col) ? 1.f : 0.f; vi[r2] = 0.f; }
        #pragma unroll
        for (int ly = 0; ly < 3; ++ly) {
            #pragma unroll
            for (int qw = 0; qw < 3; ++qw) {
                const int m = 1 << (2 - qw);                       // wire qw <-> bit 2-qw
                float a0 = prep[(ly * 3 + qw) * 2 + 0];
                float a1 = prep[(ly * 3 + qw) * 2 + 1];
                float s0, c0; sincosf(0.5f * a0, &s0, &c0);
                #pragma unroll
                for (int rr = 0; rr < 4; ++rr) {                   // RY pairs
                    const int lo = rr & (m - 1);
                    const int r0 = ((rr & ~(m - 1)) << 1) | lo;
                    const int r1 = r0 | m;
                    float t0r = c0 * vr[r0] - s0 * vr[r1], t0i = c0 * vi[r0] - s0 * vi[r1];
                    float t1r = s0 * vr[r0] + c0 * vr[r1], t1i = s0 * vi[r0] + c0 * vi[r1];
                    vr[r0] = t0r; vi[r0] = t0i; vr[r1] = t1r; vi[r1] = t1i;
                }
                float sz, cz; sincosf(0.5f * a1, &sz, &cz);
                #pragma unroll
                for (int r2 = 0; r2 < 8; ++r2) {                   // RZ: e^{-i a/2} on bit=0
                    float szz = (r2 & m) ? sz : -sz;
                    float nr = cz * vr[r2] - szz * vi[r2];
                    float ni = szz * vr[r2] + cz * vi[r2];
                    vr[r2] = nr; vi[r2] = ni;
                }
            }
            float t;
            // CNOT(0,1): ctrl bit2, tgt bit1 -> swap (4,6),(5,7)
            t = vr[4]; vr[4] = vr[6]; vr[6] = t;  t = vi[4]; vi[4] = vi[6]; vi[6] = t;
            t = vr[5]; vr[5] = vr[7]; vr[7] = t;  t = vi[5]; vi[5] = vi[7]; vi[7] = t;
            // CNOT(1,2): ctrl bit1, tgt bit0 -> swap (2,3),(6,7)
            t = vr[2]; vr[2] = vr[3]; vr[3] = t;  t = vi[2]; vi[2] = vi[3]; vi[3] = t;
            t = vr[6]; vr[6] = vr[7]; vr[7] = t;  t = vi[6]; vi[6] = vi[7]; vi[7] = t;
        }
        #pragma unroll
        for (int r2 = 0; r2 < 8; ++r2) Vl[r2 * 8 + col] = make_float2(vr[r2], vi[r2]);
    }
    __syncthreads();

    // ts = sigmoid(x W^T + b); store cos/sin(ts/2). tid<192 <-> (t,r)
    if (tid < 192) {
        int t = tid / 24, r = tid - t * 24;
        float z = bpj[r];
        for (int f = 0; f < 64; ++f)
            z += xs[f * 8 + t] * wp[f * 24 + r];
        float tv = 1.f / (1.f + expf(-z));
        csA[tid] = make_float2(cosf(0.5f * tv), sinf(0.5f * tv));
    }
    __syncthreads();

    // ---------------- state evolution ----------------
    float stx = (tid == 0) ? 1.f : 0.f;   // psi[q=0,a=0] = 1
    float sty = 0.f;

    // sim14 gate tables (nq=6): type 0=RY, 1=CRX; GA = partner-bit (RY wire bit /
    // CRX target bit), GC = CRX control bit. bit p = 5 - wire.
    constexpr int GT[24] = {0,0,0,0,0,0, 1,1,1,1,1,1, 0,0,0,0,0,0, 1,1,1,1,1,1};
    constexpr int GA[24] = {5,4,3,2,1,0, 5,0,1,2,3,4, 5,4,3,2,1,0, 1,0,5,4,3,2};
    constexpr int GC[24] = {0,0,0,0,0,0, 0,1,2,3,4,5, 0,0,0,0,0,0, 0,5,4,3,2,1};

#define APPLY_SIM14(ADJ_, UQ_)                                                \
    _Pragma("unroll")                                                         \
    for (int gi = 0; gi < 24; ++gi) {                                         \
        const int g  = (ADJ_) ? 23 - gi : gi;                                 \
        const int pb = GA[g];                                                 \
        const int addr = ((lane ^ (1 << pb)) << 2);                           \
        float2 cs = (UQ_) ? csQ[g] : csA[wid * 24 + g];                       \
        const float c = cs.x;                                                 \
        const float s = (ADJ_) ? -cs.y : cs.y;                                \
        const float prx = bperm_f(addr, stx);                                 \
        const float pry = bperm_f(addr, sty);                                 \
        if (GT[g] == 0) { /* RY: bit0: c*v0-s*v1 ; bit1: s*v0+c*v1 */         \
            const float ss = ((lane >> pb) & 1) ? s : -s;                     \
            stx = c * stx + ss * prx;                                         \
            sty = c * sty + ss * pry;                                         \
        } else {          /* CRX: ctrl=1: c*own + (-i s)*partner */           \
            const bool  ctrl = (lane >> GC[g]) & 1;                           \
            const float ce = ctrl ? c : 1.f;                                  \
            const float se = ctrl ? s : 0.f;                                  \
            const float nx = ce * stx + se * pry;                             \
            const float ny = ce * sty - se * prx;                             \
            stx = nx; sty = ny;                                               \
        }                                                                     \
    }

    auto v_apply = [&](bool dag) {
        __syncthreads();                       // previous readers done
        sl[wid * 64 + lane] = make_float2(stx, sty);
        __syncthreads();
        float ar = 0.f, ai = 0.f;
        #pragma unroll
        for (int j = 0; j < 8; ++j) {
            float2 v  = dag ? Vl[j * 8 + wid] : Vl[wid * 8 + j];
            float  vy = dag ? -v.y : v.y;
            float2 s2 = sl[j * 64 + lane];
            ar += v.x * s2.x - vy * s2.y;
            ai += v.x * s2.y + vy * s2.x;
        }
        stx = ar; sty = ai;
    };

    auto pc_phase = [&](float phi) {           // e^{+i phi} on a==0, e^{-i phi} else
        float sp, cp; sincosf(phi, &sp, &cp);
        float sg = (wid == 0) ? sp : -sp;
        float nx = stx * cp - sty * sg;
        float ny = sty * cp + stx * sg;
        stx = nx; sty = ny;
    };

    pc_phase(sig[0]);
    #pragma unroll
    for (int k = 0; k < 4; ++k) {
        v_apply(false);                        // PREPARE
        if (k & 1) { APPLY_SIM14(true, false) } else { APPLY_SIM14(false, false) }
        v_apply(true);                         // PREPARE^dag
        pc_phase(sig[k + 1]);
    }
    APPLY_SIM14(false, true)                   // QFF unitary

    // ---------------- expectations ----------------
    __syncthreads();
    sl[wid * 64 + lane] = make_float2(stx, sty);
    __syncthreads();

    if (wid < 5) {
        const int w = wid;
        const int bhp = 5 - w, blp = 4 - w;    // the two observed bits (adjacent)
        const int low_n = 4 - w;
        float ex = 0.f;
        #pragma unroll
        for (int rep = 0; rep < 2; ++rep) {
            int mm = lane + rep * 64;          // 128 (mq, a) combos
            int a  = mm & 7;
            int mq = mm >> 3;
            int qb = ((mq >> low_n) << (6 - w)) | (mq & ((1 << low_n) - 1));
            float2 p0 = sl[a * 64 + qb];
            float2 p1 = sl[a * 64 + (qb | (1 << blp))];
            float2 p2 = sl[a * 64 + (qb | (1 << bhp))];
            float2 p3 = sl[a * 64 + (qb | (1 << bhp) | (1 << blp))];
            float val = Hd_[w][0] * (p0.x * p0.x + p0.y * p0.y)
                      + Hd_[w][1] * (p1.x * p1.x + p1.y * p1.y)
                      + Hd_[w][2] * (p2.x * p2.x + p2.y * p2.y);
            // pairs (i<j): H_ij = conj(h_ji) = A - iB; term = 2*(A*Re + B*Im) of conj(pi)*pj
            val += 2.f * (HA_[w][0] * (p0.x * p1.x + p0.y * p1.y) + HB_[w][0] * (p0.x * p1.y - p0.y * p1.x));
            val += 2.f * (HA_[w][1] * (p0.x * p2.x + p0.y * p2.y) + HB_[w][1] * (p0.x * p2.y - p0.y * p2.x));
            val += 2.f * (HA_[w][2] * (p1.x * p2.x + p1.y * p2.y) + HB_[w][2] * (p1.x * p2.y - p1.y * p2.x));
            val += 2.f * (HA_[w][3] * (p0.x * p3.x + p0.y * p3.y) + HB_[w][3] * (p0.x * p3.y - p0.y * p3.x));
            val += 2.f * (HA_[w][4] * (p1.x * p3.x + p1.y * p3.y) + HB_[w][4] * (p1.x * p3.y - p1.y * p3.x));
            val += 2.f * (HA_[w][5] * (p2.x * p3.x + p2.y * p3.y) + HB_[w][5] * (p2.x * p3.y - p2.y * p3.x));
            ex += val;
        }
        #pragma unroll
        for (int m2 = 32; m2 >= 1; m2 >>= 1)
            ex += __shfl_xor(ex, m2, 64);
        if (lane == 0) exps_[w] = ex;
    }
    __syncthreads();

    if (tid < 3) {
        float r = bh[tid];
        #pragma unroll
        for (int w = 0; w < 5; ++w) r += exps_[w] * Wh[tid * 5 + w];
        out[b * 3 + tid] = r;
    }
}

extern "C" void kernel_launch(void* const* d_in, const int* in_sizes, int n_in,
                              void* d_out, int out_size, void* d_ws, size_t ws_size,
                              hipStream_t stream) {
    const int B = in_sizes[0] / (64 * 8);      // 256
    qts_kernel<<<B, 512, 0, stream>>>(
        (const float*)d_in[0], (const float*)d_in[1], (const float*)d_in[2],
        (const float*)d_in[3], (const float*)d_in[4], (const float*)d_in[5],
        (const float*)d_in[6], (const float*)d_in[7], (const float*)d_in[8],
        (const float*)d_in[9], (const float*)d_in[10],
        (float*)d_out);
}

// Round 5
// 20.447 us; speedup vs baseline: 1.0739x; 1.0739x over previous
//
#include <hip/hip_runtime.h>
#include <math.h>

// ModularQTS: B=256, F=64, NT=8, NQ=6 (DQ=64), NA=3 (DA=8), DEG=4, NROTS=24, KLOC=2.
// One block per batch element. 512 threads = 8 waves; wave = ancilla index a,
// lane = main index q. State: 1 complex amplitude per thread in VGPRs.
// Wire w <-> bit (n-1-w) (MSB-first), matching reference _ap1/_ap2 reshapes.
// Gate exchanges use VALU cross-lane (DPP quad_perm, permlane16/32_swap) where
// the XOR distance allows; ds_swizzle for xor4/xor8. No ds_bpermute on the
// critical path.

typedef unsigned u32x2_t __attribute__((ext_vector_type(2)));

__device__ __forceinline__ float bperm_f(int addr, float v) {
    return __int_as_float(__builtin_amdgcn_ds_bpermute(addr, __float_as_int(v)));
}

// v[lane ^ (1<<PB)] for all 64 lanes active.
template<int PB>
__device__ __forceinline__ float xp(float v, int lane) {
    if constexpr (PB == 0) {        // quad_perm [1,0,3,2]
        return __int_as_float(__builtin_amdgcn_update_dpp(
            __float_as_int(v), __float_as_int(v), 0xB1, 0xF, 0xF, false));
    } else if constexpr (PB == 1) { // quad_perm [2,3,0,1]
        return __int_as_float(__builtin_amdgcn_update_dpp(
            __float_as_int(v), __float_as_int(v), 0x4E, 0xF, 0xF, false));
    } else if constexpr (PB == 2) { // xor 4 within 32-lane group
        return __int_as_float(__builtin_amdgcn_ds_swizzle(__float_as_int(v), 0x101F));
    } else if constexpr (PB == 3) { // xor 8
        return __int_as_float(__builtin_amdgcn_ds_swizzle(__float_as_int(v), 0x201F));
    } else if constexpr (PB == 4) { // xor 16
#if __has_builtin(__builtin_amdgcn_permlane16_swap)
        u32x2_t r = __builtin_amdgcn_permlane16_swap(
            (unsigned)__float_as_int(v), (unsigned)__float_as_int(v), false, false);
        // r[0] rows {r0,r0,r2,r2}; r[1] rows {r1,r1,r3,r3}
        return __int_as_float((int)((lane & 16) ? r[0] : r[1]));
#else
        return __int_as_float(__builtin_amdgcn_ds_swizzle(__float_as_int(v), 0x401F));
#endif
    } else {                        // xor 32
#if __has_builtin(__builtin_amdgcn_permlane32_swap)
        u32x2_t r = __builtin_amdgcn_permlane32_swap(
            (unsigned)__float_as_int(v), (unsigned)__float_as_int(v), false, false);
        // r[0] = {lo,lo}; r[1] = {hi,hi}
        return __int_as_float((int)((lane & 32) ? r[0] : r[1]));
#else
        return bperm_f((lane ^ 32) << 2, v);
#endif
    }
}

// sim14 gate tables (nq=6): type 0=RY, 1=CRX; GA = partner bit (RY wire bit /
// CRX target bit), GC = CRX control bit. bit p = 5 - wire.
constexpr int GT[24] = {0,0,0,0,0,0, 1,1,1,1,1,1, 0,0,0,0,0,0, 1,1,1,1,1,1};
constexpr int GA[24] = {5,4,3,2,1,0, 5,0,1,2,3,4, 5,4,3,2,1,0, 1,0,5,4,3,2};
constexpr int GC[24] = {0,0,0,0,0,0, 0,1,2,3,4,5, 0,0,0,0,0,0, 0,5,4,3,2,1};

template<bool ADJ, int GI>
__device__ __forceinline__ void gate_one(float& stx, float& sty,
                                         const float2* __restrict__ cs, int lane) {
    constexpr int g  = ADJ ? 23 - GI : GI;
    constexpr int pb = GA[g];
    const float2 c_s = cs[g];
    const float c = c_s.x;
    const float s = ADJ ? -c_s.y : c_s.y;
    const float prx = xp<pb>(stx, lane);
    const float pry = xp<pb>(sty, lane);
    if constexpr (GT[g] == 0) {     // RY: bit0: c*v0 - s*v1 ; bit1: s*v0 + c*v1
        const float ss = ((lane >> pb) & 1) ? s : -s;
        stx = c * stx + ss * prx;
        sty = c * sty + ss * pry;
    } else {                        // CRX: ctrl=1: c*own + (-i s)*partner
        constexpr int cb = GC[g];
        const bool  ctrl = (lane >> cb) & 1;
        const float ce = ctrl ? c : 1.f;
        const float se = ctrl ? s : 0.f;
        const float nx = ce * stx + se * pry;
        const float ny = ce * sty - se * prx;
        stx = nx; sty = ny;
    }
}

template<bool ADJ, int GI>
__device__ __forceinline__ void gates_from(float& stx, float& sty,
                                           const float2* __restrict__ cs, int lane) {
    if constexpr (GI < 24) {
        gate_one<ADJ, GI>(stx, sty, cs, lane);
        gates_from<ADJ, GI + 1>(stx, sty, cs, lane);
    }
}

__global__ void __launch_bounds__(512)
qts_kernel(const float* __restrict__ x,      // (B,64,8)
           const float* __restrict__ Wp,     // (24,64)
           const float* __restrict__ bpj,    // (24,)
           const float* __restrict__ prep,   // (3,3,2)
           const float* __restrict__ sig,    // (5,)
           const float* __restrict__ qff,    // (24,)
           const float* __restrict__ Aoff,   // (5,6)
           const float* __restrict__ Boff,   // (5,6)
           const float* __restrict__ Ddiag,  // (5,4)
           const float* __restrict__ Wh,     // (3,5)
           const float* __restrict__ bh,     // (3,)
           float* __restrict__ out)          // (B,3)
{
    __shared__ float  xs[512];        // x[b] as [f][t]
    __shared__ float  wp[64 * 24];    // W_proj transposed [f][r]
    __shared__ float2 csA[8 * 24];    // cos/sin(ts/2), [t][r]
    __shared__ float2 csQ[24];        // cos/sin(qff/2)
    __shared__ float2 sigcs[5];       // cos/sin(sig)
    __shared__ float2 Vl[64];         // PREPARE V, [i][j]
    __shared__ float  Hd_[5][3];      // 2*D_diag[w][1..3]
    __shared__ float  HA_[5][6];
    __shared__ float  HB_[5][6];
    __shared__ float2 sl[2][512];     // state staging [buf][a*64+q]
    __shared__ float  exps_[5];

    const int tid  = threadIdx.x;
    const int lane = tid & 63;
    const int wid  = tid >> 6;        // ancilla index a
    const int b    = blockIdx.x;

    // ---------------- setup ----------------
    if (tid < 128)
        ((float4*)xs)[tid] = ((const float4*)(x + b * 512))[tid];
    for (int e = tid; e < 24 * 64; e += 512) {
        int r = e >> 6, f = e & 63;
        wp[f * 24 + r] = Wp[e];
    }
    if (tid < 24) {
        float th = 0.5f * qff[tid];
        csQ[tid] = make_float2(cosf(th), sinf(th));
    }
    if (tid >= 40 && tid < 45) {
        float ph = sig[tid - 40];
        sigcs[tid - 40] = make_float2(cosf(ph), sinf(ph));
    }
    if (tid < 5) {
        #pragma unroll
        for (int i = 0; i < 3; ++i) Hd_[tid][i] = 2.f * Ddiag[tid * 4 + i + 1];
        #pragma unroll
        for (int j = 0; j < 6; ++j) { HA_[tid][j] = Aoff[tid * 6 + j]; HB_[tid][j] = Boff[tid * 6 + j]; }
    }
    if (tid < 8) {
        // Build PREPARE V (8x8), thread owns column `col`; gates mix row index.
        const int col = tid;
        float vr[8], vi[8];
        #pragma unroll
        for (int r2 = 0; r2 < 8; ++r2) { vr[r2] = (r2 == col) ? 1.f : 0.f; vi[r2] = 0.f; }
        #pragma unroll
        for (int ly = 0; ly < 3; ++ly) {
            #pragma unroll
            for (int qw = 0; qw < 3; ++qw) {
                const int m = 1 << (2 - qw);                       // wire qw <-> bit 2-qw
                float a0 = prep[(ly * 3 + qw) * 2 + 0];
                float a1 = prep[(ly * 3 + qw) * 2 + 1];
                float s0, c0; sincosf(0.5f * a0, &s0, &c0);
                #pragma unroll
                for (int rr = 0; rr < 4; ++rr) {                   // RY pairs
                    const int lo = rr & (m - 1);
                    const int r0 = ((rr & ~(m - 1)) << 1) | lo;
                    const int r1 = r0 | m;
                    float t0r = c0 * vr[r0] - s0 * vr[r1], t0i = c0 * vi[r0] - s0 * vi[r1];
                    float t1r = s0 * vr[r0] + c0 * vr[r1], t1i = s0 * vi[r0] + c0 * vi[r1];
                    vr[r0] = t0r; vi[r0] = t0i; vr[r1] = t1r; vi[r1] = t1i;
                }
                float sz, cz; sincosf(0.5f * a1, &sz, &cz);
                #pragma unroll
                for (int r2 = 0; r2 < 8; ++r2) {                   // RZ: e^{-i a/2} on bit=0
                    float szz = (r2 & m) ? sz : -sz;
                    float nr = cz * vr[r2] - szz * vi[r2];
                    float ni = szz * vr[r2] + cz * vi[r2];
                    vr[r2] = nr; vi[r2] = ni;
                }
            }
            float t;
            // CNOT(0,1): ctrl bit2, tgt bit1 -> swap (4,6),(5,7)
            t = vr[4]; vr[4] = vr[6]; vr[6] = t;  t = vi[4]; vi[4] = vi[6]; vi[6] = t;
            t = vr[5]; vr[5] = vr[7]; vr[7] = t;  t = vi[5]; vi[5] = vi[7]; vi[7] = t;
            // CNOT(1,2): ctrl bit1, tgt bit0 -> swap (2,3),(6,7)
            t = vr[2]; vr[2] = vr[3]; vr[3] = t;  t = vi[2]; vi[2] = vi[3]; vi[3] = t;
            t = vr[6]; vr[6] = vr[7]; vr[7] = t;  t = vi[6]; vi[6] = vi[7]; vi[7] = t;
        }
        #pragma unroll
        for (int r2 = 0; r2 < 8; ++r2) Vl[r2 * 8 + col] = make_float2(vr[r2], vi[r2]);
    }
    __syncthreads();

    // ts = sigmoid(x W^T + b); store cos/sin(ts/2). tid<192 <-> (t,r)
    if (tid < 192) {
        int t = tid / 24, r = tid - t * 24;
        float z = bpj[r];
        for (int f = 0; f < 64; ++f)
            z += xs[f * 8 + t] * wp[f * 24 + r];
        float tv = 1.f / (1.f + expf(-z));
        csA[tid] = make_float2(cosf(0.5f * tv), sinf(0.5f * tv));
    }
    __syncthreads();

    // ---------------- state evolution ----------------
    float stx = (tid == 0) ? 1.f : 0.f;   // psi[q=0,a=0] = 1
    float sty = 0.f;
    int buf = 0;

    auto v_apply = [&](bool dag) {         // PREPARE / PREPARE^dag on ancilla axis
        sl[buf][wid * 64 + lane] = make_float2(stx, sty);
        __syncthreads();
        float ar = 0.f, ai = 0.f;
        #pragma unroll
        for (int j = 0; j < 8; ++j) {
            float2 v  = dag ? Vl[j * 8 + wid] : Vl[wid * 8 + j];
            float  vy = dag ? -v.y : v.y;
            float2 s2 = sl[buf][j * 64 + lane];
            ar += v.x * s2.x - vy * s2.y;
            ai += v.x * s2.y + vy * s2.x;
        }
        stx = ar; sty = ai; buf ^= 1;
    };

    auto pc_phase = [&](int k) {           // e^{+i phi} on a==0, e^{-i phi} else
        float2 cs = sigcs[k];
        float sg = (wid == 0) ? cs.y : -cs.y;
        float nx = stx * cs.x - sty * sg;
        float ny = sty * cs.x + stx * sg;
        stx = nx; sty = ny;
    };

    const float2* csW = csA + wid * 24;

    pc_phase(0);
    #pragma unroll
    for (int k = 0; k < 4; ++k) {
        v_apply(false);                    // PREPARE
        if (k & 1) gates_from<true , 0>(stx, sty, csW, lane);
        else       gates_from<false, 0>(stx, sty, csW, lane);
        v_apply(true);                     // PREPARE^dag
        pc_phase(k + 1);
    }
    gates_from<false, 0>(stx, sty, csQ, lane);   // QFF unitary

    // ---------------- expectations ----------------
    sl[buf][wid * 64 + lane] = make_float2(stx, sty);
    __syncthreads();

    if (wid < 5) {
        const int w = wid;
        const int bhp = 5 - w, blp = 4 - w;    // the two observed bits (adjacent)
        const int low_n = 4 - w;
        const float2* sb = sl[buf];
        float ex = 0.f;
        #pragma unroll
        for (int rep = 0; rep < 2; ++rep) {
            int mm = lane + rep * 64;          // 128 (mq, a) combos
            int a  = mm & 7;
            int mq = mm >> 3;
            int qb = ((mq >> low_n) << (6 - w)) | (mq & ((1 << low_n) - 1));
            float2 p0 = sb[a * 64 + qb];
            float2 p1 = sb[a * 64 + (qb | (1 << blp))];
            float2 p2 = sb[a * 64 + (qb | (1 << bhp))];
            float2 p3 = sb[a * 64 + (qb | (1 << bhp) | (1 << blp))];
            float val = Hd_[w][0] * (p0.x * p0.x + p0.y * p0.y)
                      + Hd_[w][1] * (p1.x * p1.x + p1.y * p1.y)
                      + Hd_[w][2] * (p2.x * p2.x + p2.y * p2.y);
            // pairs (i<j): H_ij = conj(h_ji) = A - iB; term = 2*(A*Re + B*Im) of conj(pi)*pj
            val += 2.f * (HA_[w][0] * (p0.x * p1.x + p0.y * p1.y) + HB_[w][0] * (p0.x * p1.y - p0.y * p1.x));
            val += 2.f * (HA_[w][1] * (p0.x * p2.x + p0.y * p2.y) + HB_[w][1] * (p0.x * p2.y - p0.y * p2.x));
            val += 2.f * (HA_[w][2] * (p1.x * p2.x + p1.y * p2.y) + HB_[w][2] * (p1.x * p2.y - p1.y * p2.x));
            val += 2.f * (HA_[w][3] * (p0.x * p3.x + p0.y * p3.y) + HB_[w][3] * (p0.x * p3.y - p0.y * p3.x));
            val += 2.f * (HA_[w][4] * (p1.x * p3.x + p1.y * p3.y) + HB_[w][4] * (p1.x * p3.y - p1.y * p3.x));
            val += 2.f * (HA_[w][5] * (p2.x * p3.x + p2.y * p3.y) + HB_[w][5] * (p2.x * p3.y - p2.y * p3.x));
            ex += val;
        }
        #pragma unroll
        for (int m2 = 32; m2 >= 1; m2 >>= 1)
            ex += __shfl_xor(ex, m2, 64);
        if (lane == 0) exps_[w] = ex;
    }
    __syncthreads();

    if (tid < 3) {
        float r = bh[tid];
        #pragma unroll
        for (int w = 0; w < 5; ++w) r += exps_[w] * Wh[tid * 5 + w];
        out[b * 3 + tid] = r;
    }
}

extern "C" void kernel_launch(void* const* d_in, const int* in_sizes, int n_in,
                              void* d_out, int out_size, void* d_ws, size_t ws_size,
                              hipStream_t stream) {
    const int B = in_sizes[0] / (64 * 8);      // 256
    qts_kernel<<<B, 512, 0, stream>>>(
        (const float*)d_in[0], (const float*)d_in[1], (const float*)d_in[2],
        (const float*)d_in[3], (const float*)d_in[4], (const float*)d_in[5],
        (const float*)d_in[6], (const float*)d_in[7], (const float*)d_in[8],
        (const float*)d_in[9], (const float*)d_in[10],
        (float*)d_out);
}

// Round 7
// 18.620 us; speedup vs baseline: 1.1793x; 1.0981x over previous
//
#include <hip/hip_runtime.h>
#include <math.h>

// ModularQTS: B=256, F=64, NT=8, NQ=6 (DQ=64), NA=3 (DA=8), DEG=4, NROTS=24, KLOC=2.
// One block per batch element. 512 threads = 8 waves; wave = ancilla index a,
// lane = main index q. 1 complex amplitude per thread in VGPRs.
// Wire w <-> bit (n-1-w) (MSB-first), matching reference _ap1/_ap2 reshapes.
//
// Structure (algebraically fused):
//   psi0 = e^{i phi0} |0>_Q (x) v0,  v0 = V[:,0]
//   for k: SELECT_k (per-wave sim14, adjoint odd k); between SELECTs apply
//     A(phi) = e^{-i phi} I + 2 i sin(phi) v0 v0^dag  (rank-1, one LDS round-trip)
//   trailing V^dag and PC(phi4) are ancilla-only -> dropped (commute with H(x)I).
//   Then QFF on main, then k-local expectations.
// All gate exchanges are VALU cross-lane (DPP / permlane swaps); gate angles are
// register-resident; no LDS on the gate critical path.

typedef unsigned u32x2_t __attribute__((ext_vector_type(2)));

__device__ __forceinline__ float bperm_f(int addr, float v) {
    return __int_as_float(__builtin_amdgcn_ds_bpermute(addr, __float_as_int(v)));
}

template<int CTRL>
__device__ __forceinline__ float dppf(float v) {
    return __int_as_float(__builtin_amdgcn_update_dpp(
        __float_as_int(v), __float_as_int(v), CTRL, 0xF, 0xF, false));
}

// v[lane ^ (1<<PB)], all 64 lanes active.
template<int PB>
__device__ __forceinline__ float xp(float v, int lane) {
    if constexpr (PB == 0) {        // quad_perm [1,0,3,2]
        return dppf<0xB1>(v);
    } else if constexpr (PB == 1) { // quad_perm [2,3,0,1]
        return dppf<0x4E>(v);
    } else if constexpr (PB == 2) { // xor4 = quad_perm[3,2,1,0] (xor3) o row_half_mirror (xor7)
        return dppf<0x141>(dppf<0x1B>(v));
    } else if constexpr (PB == 3) { // xor8 = row_ror:8 within 16-lane row (0x120+8)
        return dppf<0x128>(v);
    } else if constexpr (PB == 4) { // xor16
#if __has_builtin(__builtin_amdgcn_permlane16_swap)
        u32x2_t r = __builtin_amdgcn_permlane16_swap(
            (unsigned)__float_as_int(v), (unsigned)__float_as_int(v), false, false);
        return __int_as_float((int)((lane & 16) ? r[0] : r[1]));
#else
        return __int_as_float(__builtin_amdgcn_ds_swizzle(__float_as_int(v), 0x401F));
#endif
    } else {                        // xor32
#if __has_builtin(__builtin_amdgcn_permlane32_swap)
        u32x2_t r = __builtin_amdgcn_permlane32_swap(
            (unsigned)__float_as_int(v), (unsigned)__float_as_int(v), false, false);
        return __int_as_float((int)((lane & 32) ? r[0] : r[1]));
#else
        return bperm_f((lane ^ 32) << 2, v);
#endif
    }
}

// sim14 gate tables (nq=6): type 0=RY, 1=CRX; GA = partner bit (RY wire bit /
// CRX target bit), GC = CRX control bit. bit p = 5 - wire.
constexpr int GT[24] = {0,0,0,0,0,0, 1,1,1,1,1,1, 0,0,0,0,0,0, 1,1,1,1,1,1};
constexpr int GA[24] = {5,4,3,2,1,0, 5,0,1,2,3,4, 5,4,3,2,1,0, 1,0,5,4,3,2};
constexpr int GC[24] = {0,0,0,0,0,0, 0,1,2,3,4,5, 0,0,0,0,0,0, 0,5,4,3,2,1};

template<bool ADJ, int GI>
__device__ __forceinline__ void gate_one(float& stx, float& sty,
                                         const float2 (&cs)[24], int lane) {
    constexpr int g  = ADJ ? 23 - GI : GI;
    constexpr int pb = GA[g];
    const float c = cs[g].x;
    const float s = ADJ ? -cs[g].y : cs[g].y;
    const float prx = xp<pb>(stx, lane);
    const float pry = xp<pb>(sty, lane);
    if constexpr (GT[g] == 0) {     // RY
        const float ss = ((lane >> pb) & 1) ? s : -s;
        stx = c * stx + ss * prx;
        sty = c * sty + ss * pry;
    } else {                        // CRX: ctrl=1: c*own + (-i s)*partner
        constexpr int cb = GC[g];
        const bool  ctrl = (lane >> cb) & 1;
        const float ce = ctrl ? c : 1.f;
        const float se = ctrl ? s : 0.f;
        const float nx = ce * stx + se * pry;
        const float ny = ce * sty - se * prx;
        stx = nx; sty = ny;
    }
}

template<bool ADJ, int GI>
__device__ __forceinline__ void gates_from(float& stx, float& sty,
                                           const float2 (&cs)[24], int lane) {
    if constexpr (GI < 24) {
        gate_one<ADJ, GI>(stx, sty, cs, lane);
        gates_from<ADJ, GI + 1>(stx, sty, cs, lane);
    }
}

__global__ void __launch_bounds__(512, 2)
qts_kernel(const float* __restrict__ x,      // (B,64,8)
           const float* __restrict__ Wp,     // (24,64)
           const float* __restrict__ bpj,    // (24,)
           const float* __restrict__ prep,   // (3,3,2)
           const float* __restrict__ sig,    // (5,)
           const float* __restrict__ qff,    // (24,)
           const float* __restrict__ Aoff,   // (5,6)
           const float* __restrict__ Boff,   // (5,6)
           const float* __restrict__ Ddiag,  // (5,4)
           const float* __restrict__ Wh,     // (3,5)
           const float* __restrict__ bh,     // (3,)
           float* __restrict__ out)          // (B,3)
{
    __shared__ float  xs_t[8 * 72];   // x[b] transposed [t][f], stride 72 (bank spread)
    __shared__ float2 csA[8 * 24];    // cos/sin(ts/2), [t][r]
    __shared__ float2 csQ[24];        // cos/sin(qff/2)
    __shared__ float2 Vl[64];         // PREPARE V, [i][j]
    __shared__ float2 sl[2][512];     // state staging [buf][a*64+q]
    __shared__ float  exps_[5];

    const int tid  = threadIdx.x;
    const int lane = tid & 63;
    const int wid  = tid >> 6;        // ancilla index a
    const int b    = blockIdx.x;

    // ---------------- setup ----------------
    if (tid < 128) {
        float4 v = ((const float4*)(x + b * 512))[tid];
        int e = tid * 4;              // 4 consecutive e share f, t0..t0+3
        int f = e >> 3, t0 = e & 7;
        xs_t[t0 * 72 + f]       = v.x;
        xs_t[(t0 + 1) * 72 + f] = v.y;
        xs_t[(t0 + 2) * 72 + f] = v.z;
        xs_t[(t0 + 3) * 72 + f] = v.w;
    }
    if (tid >= 128 && tid < 152) {
        int r = tid - 128;
        float th = 0.5f * qff[r];
        csQ[r] = make_float2(cosf(th), sinf(th));
    }
    if (tid < 8) {
        // Build PREPARE V (8x8), thread owns column `col`; gates mix row index.
        const int col = tid;
        float vr[8], vi[8];
        #pragma unroll
        for (int r2 = 0; r2 < 8; ++r2) { vr[r2] = (r2 == col) ? 1.f : 0.f; vi[r2] = 0.f; }
        #pragma unroll
        for (int ly = 0; ly < 3; ++ly) {
            #pragma unroll
            for (int qw = 0; qw < 3; ++qw) {
                const int m = 1 << (2 - qw);                       // wire qw <-> bit 2-qw
                float a0 = prep[(ly * 3 + qw) * 2 + 0];
                float a1 = prep[(ly * 3 + qw) * 2 + 1];
                float s0, c0; sincosf(0.5f * a0, &s0, &c0);
                #pragma unroll
                for (int rr = 0; rr < 4; ++rr) {                   // RY pairs
                    const int lo = rr & (m - 1);
                    const int r0 = ((rr & ~(m - 1)) << 1) | lo;
                    const int r1 = r0 | m;
                    float t0r = c0 * vr[r0] - s0 * vr[r1], t0i = c0 * vi[r0] - s0 * vi[r1];
                    float t1r = s0 * vr[r0] + c0 * vr[r1], t1i = s0 * vi[r0] + c0 * vi[r1];
                    vr[r0] = t0r; vi[r0] = t0i; vr[r1] = t1r; vi[r1] = t1i;
                }
                float sz, cz; sincosf(0.5f * a1, &sz, &cz);
                #pragma unroll
                for (int r2 = 0; r2 < 8; ++r2) {                   // RZ: e^{-i a/2} on bit=0
                    float szz = (r2 & m) ? sz : -sz;
                    float nr = cz * vr[r2] - szz * vi[r2];
                    float ni = szz * vr[r2] + cz * vi[r2];
                    vr[r2] = nr; vi[r2] = ni;
                }
            }
            float t;
            // CNOT(0,1): ctrl bit2, tgt bit1 -> swap (4,6),(5,7)
            t = vr[4]; vr[4] = vr[6]; vr[6] = t;  t = vi[4]; vi[4] = vi[6]; vi[6] = t;
            t = vr[5]; vr[5] = vr[7]; vr[7] = t;  t = vi[5]; vi[5] = vi[7]; vi[7] = t;
            // CNOT(1,2): ctrl bit1, tgt bit0 -> swap (2,3),(6,7)
            t = vr[2]; vr[2] = vr[3]; vr[3] = t;  t = vi[2]; vi[2] = vi[3]; vi[3] = t;
            t = vr[6]; vr[6] = vr[7]; vr[7] = t;  t = vi[6]; vi[6] = vi[7]; vi[7] = t;
        }
        #pragma unroll
        for (int r2 = 0; r2 < 8; ++r2) Vl[r2 * 8 + col] = make_float2(vr[r2], vi[r2]);
    }
    __syncthreads();

    // ts = sigmoid(x W^T + b); store cos/sin(ts/2). tid<192 <-> (t,r)
    if (tid < 192) {
        int t = tid / 24, r = tid - t * 24;
        const float4* wr4 = (const float4*)(Wp + r * 64);
        float z = bpj[r];
        #pragma unroll
        for (int f4 = 0; f4 < 16; ++f4) {
            float4 wv = wr4[f4];
            float4 xv = *(const float4*)(xs_t + t * 72 + f4 * 4);
            z += wv.x * xv.x + wv.y * xv.y + wv.z * xv.z + wv.w * xv.w;
        }
        float tv = 1.f / (1.f + expf(-z));
        csA[tid] = make_float2(cosf(0.5f * tv), sinf(0.5f * tv));
    }
    __syncthreads();

    // ---------------- register preloads ----------------
    float2 ang[24], angQ[24];
    {
        const float2* csW = csA + wid * 24;
        #pragma unroll
        for (int g = 0; g < 24; ++g) ang[g] = csW[g];
        #pragma unroll
        for (int g = 0; g < 24; ++g) angQ[g] = csQ[g];
    }
    float2 v0a[8];
    #pragma unroll
    for (int j = 0; j < 8; ++j) v0a[j] = Vl[j * 8];     // v0 = V[:,0]
    const float2 v0w = Vl[wid * 8];                     // v0[wid]

    float sp0, cp0; sincosf(sig[0], &sp0, &cp0);
    float sp1, cp1; sincosf(sig[1], &sp1, &cp1);
    float sp2, cp2; sincosf(sig[2], &sp2, &cp2);
    float sp3, cp3; sincosf(sig[3], &sp3, &cp3);

    // ---------------- state evolution ----------------
    // psi0 = e^{i phi0} * v0[wid] on lane 0
    float stx = 0.f, sty = 0.f;
    if (lane == 0) {
        stx = cp0 * v0w.x - sp0 * v0w.y;
        sty = cp0 * v0w.y + sp0 * v0w.x;
    }
    int buf = 0;

    // A(phi) = e^{-i phi} I + 2 i sin(phi) v0 v0^dag  (on ancilla axis)
    auto anc_apply = [&](float cp, float sp) {
        sl[buf][wid * 64 + lane] = make_float2(stx, sty);
        __syncthreads();
        float sr = 0.f, si = 0.f;                       // s = v0^dag psi_{lane,:}
        #pragma unroll
        for (int j = 0; j < 8; ++j) {
            float2 p = sl[buf][j * 64 + lane];
            float2 w = v0a[j];
            sr += w.x * p.x + w.y * p.y;
            si += w.x * p.y - w.y * p.x;
        }
        const float ur = -2.f * sp * v0w.y;             // (2 i sp v0[wid])
        const float ui =  2.f * sp * v0w.x;
        const float nx = cp * stx + sp * sty + ur * sr - ui * si;
        const float ny = cp * sty - sp * stx + ur * si + ui * sr;
        stx = nx; sty = ny; buf ^= 1;
    };

    gates_from<false, 0>(stx, sty, ang, lane);          // SELECT_0
    anc_apply(cp1, sp1);
    gates_from<true , 0>(stx, sty, ang, lane);          // SELECT_1 (adj)
    anc_apply(cp2, sp2);
    gates_from<false, 0>(stx, sty, ang, lane);          // SELECT_2
    anc_apply(cp3, sp3);
    gates_from<true , 0>(stx, sty, ang, lane);          // SELECT_3 (adj)
    gates_from<false, 0>(stx, sty, angQ, lane);         // QFF unitary

    // ---------------- expectations ----------------
    sl[buf][wid * 64 + lane] = make_float2(stx, sty);
    __syncthreads();

    if (wid < 5) {
        const int w = wid;
        const int bhp = 5 - w, blp = 4 - w;    // the two observed bits (adjacent)
        const int low_n = 4 - w;
        const float2* sb = sl[buf];
        const float hd0 = 2.f * Ddiag[w * 4 + 1];
        const float hd1 = 2.f * Ddiag[w * 4 + 2];
        const float hd2 = 2.f * Ddiag[w * 4 + 3];
        float ha[6], hb[6];
        #pragma unroll
        for (int j = 0; j < 6; ++j) { ha[j] = Aoff[w * 6 + j]; hb[j] = Boff[w * 6 + j]; }
        float ex = 0.f;
        #pragma unroll
        for (int rep = 0; rep < 2; ++rep) {
            int mm = lane + rep * 64;          // 128 (mq, a) combos
            int a  = mm & 7;
            int mq = mm >> 3;
            int qb = ((mq >> low_n) << (6 - w)) | (mq & ((1 << low_n) - 1));
            float2 p0 = sb[a * 64 + qb];
            float2 p1 = sb[a * 64 + (qb | (1 << blp))];
            float2 p2 = sb[a * 64 + (qb | (1 << bhp))];
            float2 p3 = sb[a * 64 + (qb | (1 << bhp) | (1 << blp))];
            float val = hd0 * (p0.x * p0.x + p0.y * p0.y)
                      + hd1 * (p1.x * p1.x + p1.y * p1.y)
                      + hd2 * (p2.x * p2.x + p2.y * p2.y);
            // pairs (i<j) in tril order; term = 2*(A*Re + B*Im) of conj(pi)*pj
            val += 2.f * (ha[0] * (p0.x * p1.x + p0.y * p1.y) + hb[0] * (p0.x * p1.y - p0.y * p1.x));
            val += 2.f * (ha[1] * (p0.x * p2.x + p0.y * p2.y) + hb[1] * (p0.x * p2.y - p0.y * p2.x));
            val += 2.f * (ha[2] * (p1.x * p2.x + p1.y * p2.y) + hb[2] * (p1.x * p2.y - p1.y * p2.x));
            val += 2.f * (ha[3] * (p0.x * p3.x + p0.y * p3.y) + hb[3] * (p0.x * p3.y - p0.y * p3.x));
            val += 2.f * (ha[4] * (p1.x * p3.x + p1.y * p3.y) + hb[4] * (p1.x * p3.y - p1.y * p3.x));
            val += 2.f * (ha[5] * (p2.x * p3.x + p2.y * p3.y) + hb[5] * (p2.x * p3.y - p2.y * p3.x));
            ex += val;
        }
        // DPP butterfly all-reduce across the wave
        ex += xp<0>(ex, lane); ex += xp<1>(ex, lane); ex += xp<2>(ex, lane);
        ex += xp<3>(ex, lane); ex += xp<4>(ex, lane); ex += xp<5>(ex, lane);
        if (lane == 0) exps_[w] = ex;
    }
    __syncthreads();

    if (tid < 3) {
        float r = bh[tid];
        #pragma unroll
        for (int w = 0; w < 5; ++w) r += exps_[w] * Wh[tid * 5 + w];
        out[b * 3 + tid] = r;
    }
}

extern "C" void kernel_launch(void* const* d_in, const int* in_sizes, int n_in,
                              void* d_out, int out_size, void* d_ws, size_t ws_size,
                              hipStream_t stream) {
    const int B = in_sizes[0] / (64 * 8);      // 256
    qts_kernel<<<B, 512, 0, stream>>>(
        (const float*)d_in[0], (const float*)d_in[1], (const float*)d_in[2],
        (const float*)d_in[3], (const float*)d_in[4], (const float*)d_in[5],
        (const float*)d_in[6], (const float*)d_in[7], (const float*)d_in[8],
        (const float*)d_in[9], (const float*)d_in[10],
        (float*)d_out);
}